// Round 4
// baseline (286.651 us; speedup 1.0000x reference)
//
#include <hip/hip_runtime.h>
#include <stdint.h>

// GroupASL: out[b,g,k] = <h[b,g,:]/||h||, W[g,:,k]/||W_col||>
// B=512, G=100, D=768, K=100. f32 in/out; bf16 MFMA inside.
// Norms deferred to epilogue: out = dot_bf16(h_raw, W_raw) * invh[b] * invw[k].

#define G_    100
#define D_    768
#define K_    100
#define B_    512
#define KP_   128          // N padded to 8*16 (rows 100..127 zero)
#define BM    64           // M tile: 4 waves x 16 rows
#define BK    64           // K step (2 mfma k-subs of 32)
#define NT    7            // N tiles of 16 actually computed (cols 0..111)
#define NITER (D_ / BK)    // 12

typedef __attribute__((ext_vector_type(8))) short bf16x8;
typedef __attribute__((ext_vector_type(4))) float f32x4;

__device__ __forceinline__ short f2bf(float f) {
    // round-to-nearest-even f32 -> bf16
    uint32_t u = __builtin_bit_cast(uint32_t, f);
    u = (u + 0x7FFFu + ((u >> 16) & 1u)) >> 16;
    return (short)u;
}

__device__ __forceinline__ void gl_lds16(const void* g, void* l) {
    // async global->LDS, 16B per lane; LDS dest = wave-uniform base + lane*16
    __builtin_amdgcn_global_load_lds(
        (const __attribute__((address_space(1))) uint32_t*)g,
        (__attribute__((address_space(3))) uint32_t*)l, 16, 0, 0);
}

// ---------- Kernel 1: W transpose+cast + partial column sumsq ----------
// Wt[g][kp][d] bf16 (kp in [0,128), rows>=100 zero); wpart[g][dc][kp] f32.
// Block = (g, 64-row d-chunk). 1200 blocks.
__global__ __launch_bounds__(256) void wprep(const float* __restrict__ W,
                                             short* __restrict__ Wt,
                                             float* __restrict__ wpart) {
    int bid = blockIdx.x;            // g*12 + dc
    int g = bid / 12, dc = bid % 12;
    int d0 = dc * 64;
    int t = threadIdx.x;
    __shared__ float tile[64][104];  // 104: transposed column reads 2-way-bank (free)

    for (int s = t; s < 64 * 25; s += 256) {   // 64 rows x 25 float4 (100 f32/row)
        int d = s / 25, j = s % 25;
        const float4 v = *(const float4*)(W + ((size_t)(g * D_ + d0 + d)) * K_ + j * 4);
        tile[d][j * 4 + 0] = v.x; tile[d][j * 4 + 1] = v.y;
        tile[d][j * 4 + 2] = v.z; tile[d][j * 4 + 3] = v.w;
    }
    __syncthreads();

    int kp = t >> 1, h2 = t & 1;     // thread -> (W column, 32-d half)
    float ss = 0.f;
    short* dst = Wt + ((size_t)(g * KP_ + kp)) * D_ + d0 + h2 * 32;
    if (kp < K_) {
        #pragma unroll
        for (int c = 0; c < 4; ++c) {
            bf16x8 o;
            #pragma unroll
            for (int i = 0; i < 8; ++i) {
                float v = tile[h2 * 32 + c * 8 + i][kp];
                ss += v * v;
                o[i] = f2bf(v);
            }
            *(bf16x8*)(dst + c * 8) = o;
        }
    } else {
        bf16x8 z = {0, 0, 0, 0, 0, 0, 0, 0};
        #pragma unroll
        for (int c = 0; c < 4; ++c) *(bf16x8*)(dst + c * 8) = z;
    }
    ss += __shfl_xor(ss, 1);         // combine the two halves of this column chunk
    if (h2 == 0) wpart[(size_t)(g * 12 + dc) * KP_ + kp] = ss;
}

// ---------- Kernel 2: per-group GEMM, A in registers, B async->LDS ----------
// 800 blocks x 256 thr. Block = (g, 64-row m-tile).
__global__ __launch_bounds__(256) void gemm(const float* __restrict__ h,
                                            const short* __restrict__ Wt,
                                            const float* __restrict__ wpart,
                                            float* __restrict__ out) {
    // XCD-chunked mapping: a group's 8 m-tiles land on ONE XCD (bid%8 const)
    // so the 196KB Wt slice is fetched into one L2 and shared.
    int bid = blockIdx.x;
    int g, mt;
    if (bid < 768) { g = (bid & 7) + 8 * (bid >> 6); mt = (bid >> 3) & 7; }
    else           { int l = bid - 768; g = 96 + (l & 3); mt = l >> 2; }  // tail: groups 96..99
    int b0 = mt * BM;
    int t = threadIdx.x;
    int w = t >> 6, lane = t & 63;
    int r = lane & 15, hh = lane >> 4;

    __shared__ __align__(16) short Bs[2][KP_ * BK];  // 2 x 16KB, XOR-swizzled rows
    __shared__ float invw[KP_];
    __shared__ float hss[BM];

    const short* wtg = Wt + (size_t)g * KP_ * D_;

    // inverse W-column norms from the 12 partials (tiny, L2-resident)
    if (t < KP_) {
        float s2 = 0.f;
        #pragma unroll
        for (int c = 0; c < 12; ++c) s2 += wpart[(size_t)(g * 12 + c) * KP_ + t];
        invw[t] = 1.f / fmaxf(sqrtf(s2), 1e-12f);
    }

    // per-lane A source: row b0+w*16+r, k chunk base hh*8 (exact A-frag layout)
    const float* hp = h + ((size_t)((b0 + w * 16 + r) * G_ + g)) * D_ + hh * 8;

    // stage B(kt) into Bs[p]: wave w covers 1KB chunks w*4+i. Linear LDS dest,
    // inverse-swizzled per-lane GLOBAL source (rule #21): LDS (kp,colb) holds
    // global column colb ^ ((kp&7)<<4).
    auto stageB = [&](int kt, int p) {
        char* base = (char*)&Bs[p][0];
        #pragma unroll
        for (int i = 0; i < 4; ++i) {
            int c = w * 4 + i;
            int kp = c * 8 + (lane >> 3);
            int colb = (lane & 7) * 16;
            int scol = colb ^ ((kp & 7) << 4);
            const char* src = (const char*)(wtg + (size_t)kp * D_ + kt * BK) + scol;
            gl_lds16(src, base + c * 1024);
        }
    };

    f32x4 acc[NT];
    #pragma unroll
    for (int i = 0; i < NT; ++i) acc[i] = (f32x4){0.f, 0.f, 0.f, 0.f};
    float ss = 0.f;

    // prologue: issue step 0
    stageB(0, 0);
    float4 a00 = *(const float4*)(hp + 0);
    float4 a01 = *(const float4*)(hp + 4);
    float4 a10 = *(const float4*)(hp + 32);
    float4 a11 = *(const float4*)(hp + 36);

    for (int kt = 0; kt < NITER; ++kt) {
        int p = kt & 1;
        // one barrier/iter: compiler's pre-barrier vmcnt(0)+lgkmcnt(0) drain is
        // exactly the depth-1 wait needed (B(kt),A(kt) arrived; buf[p^1] reads done)
        __syncthreads();

        float4 n00 = {0,0,0,0}, n01 = {0,0,0,0}, n10 = {0,0,0,0}, n11 = {0,0,0,0};
        if (kt + 1 < NITER) {
            stageB(kt + 1, p ^ 1);
            const float* np = hp + (kt + 1) * BK;
            n00 = *(const float4*)(np + 0);
            n01 = *(const float4*)(np + 4);
            n10 = *(const float4*)(np + 32);
            n11 = *(const float4*)(np + 36);
        }

        // convert A(kt) f32->bf16 + fused row sumsq (static indices only)
        float av[16] = {a00.x, a00.y, a00.z, a00.w, a01.x, a01.y, a01.z, a01.w,
                        a10.x, a10.y, a10.z, a10.w, a11.x, a11.y, a11.z, a11.w};
        bf16x8 af0, af1;
        #pragma unroll
        for (int i = 0; i < 8; ++i) { ss += av[i] * av[i];         af0[i] = f2bf(av[i]); }
        #pragma unroll
        for (int i = 0; i < 8; ++i) { ss += av[8 + i] * av[8 + i]; af1[i] = f2bf(av[8 + i]); }

        const char* bb = (const char*)&Bs[p][0];
        int swz = (r & 7) << 4;
        #pragma unroll
        for (int nt = 0; nt < NT; ++nt) {
            int rowb = (nt * 16 + r) * 128;
            bf16x8 bv0 = *(const bf16x8*)(bb + rowb + ((hh * 16) ^ swz));
            bf16x8 bv1 = *(const bf16x8*)(bb + rowb + ((64 + hh * 16) ^ swz));
            acc[nt] = __builtin_amdgcn_mfma_f32_16x16x32_bf16(af0, bv0, acc[nt], 0, 0, 0);
            acc[nt] = __builtin_amdgcn_mfma_f32_16x16x32_bf16(af1, bv1, acc[nt], 0, 0, 0);
        }
        a00 = n00; a01 = n01; a10 = n10; a11 = n11;
    }

    // h row-sumsq: lanes {r, r+16, r+32, r+48} hold partials of row r
    ss += __shfl_xor(ss, 16);
    ss += __shfl_xor(ss, 32);
    if (hh == 0) hss[w * 16 + r] = ss;
    __syncthreads();

    // epilogue: C/D col=lane&15, row=(lane>>4)*4+reg [m89-verified]
    int rbase = hh * 4;
    float ih[4];
    #pragma unroll
    for (int q = 0; q < 4; ++q) ih[q] = 1.f / fmaxf(sqrtf(hss[w * 16 + rbase + q]), 1e-12f);
    #pragma unroll
    for (int nt = 0; nt < NT; ++nt) {
        int n = nt * 16 + r;
        if (n < K_) {
            float iw = invw[n];
            #pragma unroll
            for (int q = 0; q < 4; ++q) {
                int b = b0 + w * 16 + rbase + q;
                out[((size_t)b * G_ + g) * K_ + n] = acc[nt][q] * iw * ih[q];
            }
        }
    }
}

extern "C" void kernel_launch(void* const* d_in, const int* in_sizes, int n_in,
                              void* d_out, int out_size, void* d_ws, size_t ws_size,
                              hipStream_t stream) {
    const float* h = (const float*)d_in[0];
    const float* W = (const float*)d_in[1];
    // d_in[2] (out_extrap) unused by the reference math.
    float* out = (float*)d_out;

    short* Wt    = (short*)d_ws;                                   // 100*128*768*2 = 19.66 MB
    float* wpart = (float*)((char*)d_ws + (size_t)G_ * KP_ * D_ * 2); // +614 KB

    wprep<<<dim3(G_ * 12), dim3(256), 0, stream>>>(W, Wt, wpart);
    gemm <<<dim3(G_ * 8),  dim3(256), 0, stream>>>(h, Wt, wpart, out);
}